// Round 3
// baseline (599.484 us; speedup 1.0000x reference)
//
#include <hip/hip_runtime.h>
#include <hip/hip_bf16.h>

// SelfAttentionTransformer: B=4, L=2048, D=256, H=8, dk=32, F=1024
// All inputs AND output are float32 (proven: round-1 bf16-read -> NaN;
// round-2 bf16 write -> garbage-packed f32 readback).
// Algebraic simplifications:
//  - scores S[i,j] = sin^2(0.5*clip(m_i . m_j)) shared across batch & heads
//  - attn is head-independent => attn_out[b] = softmax_rows(masked S) @ X[b]

#define B_ 4
#define L_ 2048
#define D_ 256
#define F_ 1024
#define PI_F 3.14159265358979323846f

// ---------------- m = mean over (b,h) of xh : [L, 32] ----------------
__global__ __launch_bounds__(256) void k_mean(const float* __restrict__ x, float* __restrict__ m) {
    int idx = blockIdx.x * 256 + threadIdx.x;   // L*32 = 65536
    int l = idx >> 5, k = idx & 31;
    float s = 0.f;
#pragma unroll
    for (int b = 0; b < B_; b++) {
        const float* xp = x + ((size_t)(b * L_ + l)) * D_ + k;
#pragma unroll
        for (int h = 0; h < 8; h++) s += xp[h * 32];
    }
    m[idx] = s * (1.f / 32.f);
}

// ---------------- S[i,j] = sin^2(0.5*clip(m_i.m_j,-pi,pi)) ----------------
__global__ __launch_bounds__(256) void k_scores(const float* __restrict__ m, float* __restrict__ S) {
    __shared__ float mi[32][33], mj[32][33];
    int bi = blockIdx.y * 32, bj = blockIdx.x * 32;
    int t = threadIdx.x;
#pragma unroll
    for (int r = 0; r < 4; r++) {
        int e = t + r * 256; int row = e >> 5, col = e & 31;
        mi[row][col] = m[(bi + row) * 32 + col];
        mj[row][col] = m[(bj + row) * 32 + col];
    }
    __syncthreads();
#pragma unroll
    for (int r = 0; r < 4; r++) {
        int e = t + r * 256; int i = e >> 5, j = e & 31;
        float d = 0.f;
#pragma unroll
        for (int k = 0; k < 32; k++) d = fmaf(mi[i][k], mj[j][k], d);
        d = fminf(fmaxf(d, -PI_F), PI_F);
        float sn = __sinf(0.5f * d);
        S[(size_t)(bi + i) * L_ + (bj + j)] = sn * sn;
    }
}

// ---------------- per (b,row) masked softmax stats ----------------
__global__ __launch_bounds__(256) void k_rowstats(const float* __restrict__ S, const int* __restrict__ mask,
                                                  float* __restrict__ rowM, float* __restrict__ rowZ) {
    int b = blockIdx.x >> 11, i = blockIdx.x & (L_ - 1);
    int t = threadIdx.x;
    const float* Srow = S + (size_t)i * L_;
    const int* mrow = mask + b * L_;
    float vals[8];
    float mx = -3e38f;
#pragma unroll
    for (int c = 0; c < 8; c++) {
        int j = t + c * 256;
        float v = mrow[j] ? Srow[j] : -1e9f;
        vals[c] = v;
        mx = fmaxf(mx, v);
    }
    __shared__ float sm[4];
#pragma unroll
    for (int o = 1; o < 64; o <<= 1) mx = fmaxf(mx, __shfl_xor(mx, o));
    if ((t & 63) == 0) sm[t >> 6] = mx;
    __syncthreads();
    mx = fmaxf(fmaxf(sm[0], sm[1]), fmaxf(sm[2], sm[3]));
    float s = 0.f;
#pragma unroll
    for (int c = 0; c < 8; c++) s += __expf(vals[c] - mx);
#pragma unroll
    for (int o = 1; o < 64; o <<= 1) s += __shfl_xor(s, o);
    __syncthreads();
    if ((t & 63) == 0) sm[t >> 6] = s;
    __syncthreads();
    s = sm[0] + sm[1] + sm[2] + sm[3];
    if (t == 0) { rowM[blockIdx.x] = mx; rowZ[blockIdx.x] = 1.0f / s; }
}

// ---------------- y1 = x + P_b @ X_b  (fused softmax-apply + AV GEMM + residual) ----------------
// 16 output rows per block; t = output column d in [0,256). grid (128, B)
__global__ __launch_bounds__(256) void k_av(const float* __restrict__ S,
                                            const float* __restrict__ rowM, const float* __restrict__ rowZ,
                                            const float* __restrict__ x, const int* __restrict__ mask,
                                            float* __restrict__ y1) {
    int b = blockIdx.y;
    int i0 = blockIdx.x * 16;
    int t = threadIdx.x;
    __shared__ float p[16][36];          // 36: keeps float4 rows 16B-aligned
    float acc[16];
#pragma unroll
    for (int m = 0; m < 16; m++) acc[m] = 0.f;

    for (int j0 = 0; j0 < L_; j0 += 32) {
        __syncthreads();
#pragma unroll
        for (int r = 0; r < 2; r++) {
            int e = t + r * 256;
            int mrow = e >> 5, j = e & 31;
            int gj = j0 + j;
            float sv = mask[b * L_ + gj] ? S[(size_t)(i0 + mrow) * L_ + gj] : -1e9f;
            int ridx = b * L_ + i0 + mrow;
            p[mrow][j] = __expf(sv - rowM[ridx]) * rowZ[ridx];
        }
        __syncthreads();
        const float* xp = x + ((size_t)(b * L_ + j0)) * D_ + t;
#pragma unroll 2
        for (int k = 0; k < 32; k += 4) {
            float x0 = xp[(k + 0) * D_];
            float x1 = xp[(k + 1) * D_];
            float x2 = xp[(k + 2) * D_];
            float x3 = xp[(k + 3) * D_];
#pragma unroll
            for (int m = 0; m < 16; m++) {
                float4 pv = *(const float4*)&p[m][(k & 31)];
                acc[m] = fmaf(pv.x, x0, acc[m]);
                acc[m] = fmaf(pv.y, x1, acc[m]);
                acc[m] = fmaf(pv.z, x2, acc[m]);
                acc[m] = fmaf(pv.w, x3, acc[m]);
            }
        }
    }
#pragma unroll
    for (int m = 0; m < 16; m++) {
        size_t idx = ((size_t)(b * L_ + i0 + m)) * D_ + t;
        y1[idx] = acc[m] + x[idx];
    }
}

// ---------------- LayerNorm over D=256 (one block per token) ----------------
__global__ __launch_bounds__(256) void k_ln(const float* __restrict__ in,
                                            const float* __restrict__ g_, const float* __restrict__ be_,
                                            float* __restrict__ outf) {
    int tok = blockIdx.x;
    int t = threadIdx.x;
    float v = in[(size_t)tok * D_ + t];
    float s = v, s2 = v * v;
    __shared__ float sm[8];
#pragma unroll
    for (int o = 1; o < 64; o <<= 1) { s += __shfl_xor(s, o); s2 += __shfl_xor(s2, o); }
    if ((t & 63) == 0) { sm[t >> 6] = s; sm[4 + (t >> 6)] = s2; }
    __syncthreads();
    s = sm[0] + sm[1] + sm[2] + sm[3];
    s2 = sm[4] + sm[5] + sm[6] + sm[7];
    float mu = s * (1.f / 256.f);
    float var = s2 * (1.f / 256.f) - mu * mu;
    float r = rsqrtf(var + 1e-5f);
    outf[(size_t)tok * D_ + t] = (v - mu) * r * g_[t] + be_[t];
}

// ---------------- GEMM1: t1 = relu(h[8192,256] @ W1[256,1024] + b1) ----------------
__global__ __launch_bounds__(256) void k_gemm1(const float* __restrict__ A, const float* __restrict__ W,
                                               const float* __restrict__ bias, float* __restrict__ out) {
    __shared__ float As[16][128];
    __shared__ float Bs[16][128];
    int m0 = blockIdx.y * 128, n0 = blockIdx.x * 128;
    int t = threadIdx.x, tx = t & 15, ty = t >> 4;
    float acc[8][8] = {};
    for (int k0 = 0; k0 < 256; k0 += 16) {
        int row = t >> 1, seg = t & 1;
        const float* ap = A + (size_t)(m0 + row) * 256 + k0 + seg * 8;
        float4 a0 = *(const float4*)ap;
        float4 a1 = *(const float4*)(ap + 4);
        int brow = t >> 4, bcol = (t & 15) * 8;
        const float* bp = W + (size_t)(k0 + brow) * 1024 + n0 + bcol;
        float4 bl0 = *(const float4*)bp;
        float4 bl1 = *(const float4*)(bp + 4);
        __syncthreads();
        int kk = seg * 8;
        As[kk + 0][row] = a0.x; As[kk + 1][row] = a0.y; As[kk + 2][row] = a0.z; As[kk + 3][row] = a0.w;
        As[kk + 4][row] = a1.x; As[kk + 5][row] = a1.y; As[kk + 6][row] = a1.z; As[kk + 7][row] = a1.w;
        *(float4*)&Bs[brow][bcol] = bl0;
        *(float4*)&Bs[brow][bcol + 4] = bl1;
        __syncthreads();
#pragma unroll
        for (int k = 0; k < 16; k++) {
            float av[8], bv[8];
            *(float4*)&av[0] = *(const float4*)&As[k][ty * 8];
            *(float4*)&av[4] = *(const float4*)&As[k][ty * 8 + 4];
            *(float4*)&bv[0] = *(const float4*)&Bs[k][tx * 8];
            *(float4*)&bv[4] = *(const float4*)&Bs[k][tx * 8 + 4];
#pragma unroll
            for (int i = 0; i < 8; i++)
#pragma unroll
                for (int j = 0; j < 8; j++) acc[i][j] = fmaf(av[i], bv[j], acc[i][j]);
        }
    }
    float bvals[8];
#pragma unroll
    for (int j = 0; j < 8; j++) bvals[j] = bias[n0 + tx * 8 + j];
#pragma unroll
    for (int i = 0; i < 8; i++) {
        size_t rr = m0 + ty * 8 + i;
        float4 o0, o1;
        o0.x = fmaxf(acc[i][0] + bvals[0], 0.f);
        o0.y = fmaxf(acc[i][1] + bvals[1], 0.f);
        o0.z = fmaxf(acc[i][2] + bvals[2], 0.f);
        o0.w = fmaxf(acc[i][3] + bvals[3], 0.f);
        o1.x = fmaxf(acc[i][4] + bvals[4], 0.f);
        o1.y = fmaxf(acc[i][5] + bvals[5], 0.f);
        o1.z = fmaxf(acc[i][6] + bvals[6], 0.f);
        o1.w = fmaxf(acc[i][7] + bvals[7], 0.f);
        *(float4*)&out[rr * 1024 + n0 + tx * 8] = o0;
        *(float4*)&out[rr * 1024 + n0 + tx * 8 + 4] = o1;
    }
}

// ---------------- GEMM2: y2 = h + t1[8192,1024] @ W2[1024,256] + b2 ----------------
__global__ __launch_bounds__(256) void k_gemm2(const float* __restrict__ A, const float* __restrict__ W,
                                               const float* __restrict__ bias, const float* __restrict__ resid,
                                               float* __restrict__ out) {
    __shared__ float As[16][128];
    __shared__ float Bs[16][64];
    int m0 = blockIdx.y * 128, n0 = blockIdx.x * 64;
    int t = threadIdx.x, tx = t & 15, ty = t >> 4;
    float acc[8][4] = {};
    for (int k0 = 0; k0 < 1024; k0 += 16) {
        int row = t >> 1, seg = t & 1;
        const float* ap = A + (size_t)(m0 + row) * 1024 + k0 + seg * 8;
        float4 a0 = *(const float4*)ap;
        float4 a1 = *(const float4*)(ap + 4);
        int brow = t >> 4, bcol = (t & 15) * 4;
        float4 bl = *(const float4*)(W + (size_t)(k0 + brow) * 256 + n0 + bcol);
        __syncthreads();
        int kk = seg * 8;
        As[kk + 0][row] = a0.x; As[kk + 1][row] = a0.y; As[kk + 2][row] = a0.z; As[kk + 3][row] = a0.w;
        As[kk + 4][row] = a1.x; As[kk + 5][row] = a1.y; As[kk + 6][row] = a1.z; As[kk + 7][row] = a1.w;
        *(float4*)&Bs[brow][bcol] = bl;
        __syncthreads();
#pragma unroll
        for (int k = 0; k < 16; k++) {
            float av[8], bv[4];
            *(float4*)&av[0] = *(const float4*)&As[k][ty * 8];
            *(float4*)&av[4] = *(const float4*)&As[k][ty * 8 + 4];
            *(float4*)&bv[0] = *(const float4*)&Bs[k][tx * 4];
#pragma unroll
            for (int i = 0; i < 8; i++)
#pragma unroll
                for (int j = 0; j < 4; j++) acc[i][j] = fmaf(av[i], bv[j], acc[i][j]);
        }
    }
    int cc = n0 + tx * 4;
    float b0 = bias[cc + 0], b1v = bias[cc + 1], b2v = bias[cc + 2], b3 = bias[cc + 3];
#pragma unroll
    for (int i = 0; i < 8; i++) {
        size_t rr = m0 + ty * 8 + i;
        float4 rv = *(const float4*)&resid[rr * 256 + cc];
        float4 o;
        o.x = rv.x + acc[i][0] + b0;
        o.y = rv.y + acc[i][1] + b1v;
        o.z = rv.z + acc[i][2] + b2v;
        o.w = rv.w + acc[i][3] + b3;
        *(float4*)&out[rr * 256 + cc] = o;
    }
}

extern "C" void kernel_launch(void* const* d_in, const int* in_sizes, int n_in,
                              void* d_out, int out_size, void* d_ws, size_t ws_size,
                              hipStream_t stream) {
    const float* x   = (const float*)d_in[0];
    const int*  mask = (const int*)d_in[1];
    const float* W1  = (const float*)d_in[2];
    const float* b1  = (const float*)d_in[3];
    const float* W2  = (const float*)d_in[4];
    const float* b2  = (const float*)d_in[5];
    const float* g1  = (const float*)d_in[6];
    const float* be1 = (const float*)d_in[7];
    const float* g2  = (const float*)d_in[8];
    const float* be2 = (const float*)d_in[9];
    float* out = (float*)d_out;

    float* ws = (float*)d_ws;
    float* m_    = ws;                 // 65536
    float* S_    = m_ + 65536;         // 4194304 (16 MB)
    float* rowM_ = S_ + 4194304;       // 8192
    float* rowZ_ = rowM_ + 8192;       // 8192
    float* y1_   = rowZ_ + 8192;       // 2097152
    float* h_    = y1_ + 2097152;      // 2097152
    float* t1_   = h_ + 2097152;       // 8388608 (32 MB)
    float* y2_   = y1_;                // reuse: y1 dead after ln1

    k_mean<<<256, 256, 0, stream>>>(x, m_);
    k_scores<<<dim3(64, 64), 256, 0, stream>>>(m_, S_);
    k_rowstats<<<B_ * L_, 256, 0, stream>>>(S_, mask, rowM_, rowZ_);
    k_av<<<dim3(128, B_), 256, 0, stream>>>(S_, rowM_, rowZ_, x, mask, y1_);
    k_ln<<<B_ * L_, 256, 0, stream>>>(y1_, g1, be1, h_);
    k_gemm1<<<dim3(8, 64), 256, 0, stream>>>(h_, W1, b1, t1_);
    k_gemm2<<<dim3(4, 64), 256, 0, stream>>>(t1_, W2, b2, h_, y2_);
    k_ln<<<B_ * L_, 256, 0, stream>>>(y2_, g2, be2, out);
}

// Round 4
// 188.591 us; speedup vs baseline: 3.1788x; 3.1788x over previous
//
#include <hip/hip_runtime.h>
#include <hip/hip_bf16.h>

// SelfAttentionTransformer: B=4, L=2048, D=256, H=8, dk=32, F=1024
// f32 inputs / f32 output (established rounds 1-3).
// Round 4: all three GEMMs on bf16 MFMA.
//  - E[i,j] = exp(sin^2(0.5*clip(m_i.m_j))) in [1,e] -> softmax without max-sub:
//    attn[b,i,:] = (sum_j E[i,j]*xm[b,j,:]) / (sum_j E[i,j]*mask[b,j])
//  - AV over all batches = ONE GEMM: E[2048,2048] @ XmT^T, XmT[n=(b,d)][j]
//  - FFN GEMM1/GEMM2 with pre-transposed bf16 weights, fused epilogues.

#define B_ 4
#define L_ 2048
#define D_ 256
#define F_ 1024
#define PI_F 3.14159265358979323846f

typedef __bf16 bf16x8 __attribute__((ext_vector_type(8)));
typedef float floatx4 __attribute__((ext_vector_type(4)));

__device__ __forceinline__ unsigned short f2bf(float f) {
    unsigned int u = __float_as_uint(f);
    u = (u + 0x7FFFu + ((u >> 16) & 1u)) >> 16;   // round-to-nearest-even
    return (unsigned short)u;
}
__device__ __forceinline__ float bf2f(unsigned short u) {
    union { unsigned int i; float f; } v; v.i = ((unsigned int)u) << 16; return v.f;
}

// ---------------- m = mean over (b,h) of xh : [L, 32] ----------------
__global__ __launch_bounds__(256) void k_mean(const float* __restrict__ x, float* __restrict__ m) {
    int idx = blockIdx.x * 256 + threadIdx.x;   // L*32 = 65536
    int l = idx >> 5, k = idx & 31;
    float s = 0.f;
#pragma unroll
    for (int b = 0; b < B_; b++) {
        const float* xp = x + ((size_t)(b * L_ + l)) * D_ + k;
#pragma unroll
        for (int h = 0; h < 8; h++) s += xp[h * 32];
    }
    m[idx] = s * (1.f / 32.f);
}

// ---------------- E[i,j] = exp(sin^2(0.5*clip(m_i.m_j,-pi,pi))) as bf16 ----------------
__global__ __launch_bounds__(256) void k_scoresE(const float* __restrict__ m, unsigned short* __restrict__ E) {
    __shared__ float mi[32][33], mj[32][33];
    int bi = blockIdx.y * 32, bj = blockIdx.x * 32;
    int t = threadIdx.x;
#pragma unroll
    for (int r = 0; r < 4; r++) {
        int e = t + r * 256; int row = e >> 5, col = e & 31;
        mi[row][col] = m[(bi + row) * 32 + col];
        mj[row][col] = m[(bj + row) * 32 + col];
    }
    __syncthreads();
#pragma unroll
    for (int r = 0; r < 4; r++) {
        int e = t + r * 256; int i = e >> 5, j = e & 31;
        float d = 0.f;
#pragma unroll
        for (int k = 0; k < 32; k++) d = fmaf(mi[i][k], mj[j][k], d);
        d = fminf(fmaxf(d, -PI_F), PI_F);
        float sn = __sinf(0.5f * d);
        E[(size_t)(bi + i) * L_ + (bj + j)] = f2bf(__expf(sn * sn));
    }
}

// ---------------- generic f32 [R,C] -> bf16 [C,R] transpose, optional row-mask ----------------
// grid (C/32, R/32, Z); batch strides R*C on both sides; mask stride R (indexed by r)
__global__ __launch_bounds__(256) void k_transpose(const float* __restrict__ in, unsigned short* __restrict__ out,
                                                   int R, int C, const int* __restrict__ mask) {
    __shared__ float tile[32][33];
    int r0 = blockIdx.y * 32, c0 = blockIdx.x * 32;
    size_t bo = (size_t)blockIdx.z * R * C;
    int t = threadIdx.x, tx = t & 31, ty = t >> 5;  // ty in [0,8)
#pragma unroll
    for (int rr = 0; rr < 4; rr++) {
        int r = ty + rr * 8;
        tile[r][tx] = in[bo + (size_t)(r0 + r) * C + c0 + tx];
    }
    float mfac = 1.f;
    if (mask) mfac = mask[(size_t)blockIdx.z * R + r0 + tx] ? 1.f : 0.f;
    __syncthreads();
#pragma unroll
    for (int rr = 0; rr < 4; rr++) {
        int c = ty + rr * 8;
        out[bo + (size_t)(c0 + c) * R + r0 + tx] = f2bf(tile[tx][c] * mfac);
    }
}

// ---------------- rsinv[b,i] = 1 / sum_j mask[b,j]*E[i,j] ----------------
__global__ __launch_bounds__(256) void k_rowsum(const unsigned short* __restrict__ E, const int* __restrict__ mask,
                                                float* __restrict__ rsinv) {
    int i = blockIdx.x, t = threadIdx.x;
    float p0 = 0.f, p1 = 0.f, p2 = 0.f, p3 = 0.f;
#pragma unroll
    for (int c = 0; c < 8; c++) {
        int j = t + c * 256;
        float e = bf2f(E[(size_t)i * L_ + j]);
        if (mask[j]) p0 += e;
        if (mask[L_ + j]) p1 += e;
        if (mask[2 * L_ + j]) p2 += e;
        if (mask[3 * L_ + j]) p3 += e;
    }
#pragma unroll
    for (int o = 1; o < 64; o <<= 1) {
        p0 += __shfl_xor(p0, o); p1 += __shfl_xor(p1, o);
        p2 += __shfl_xor(p2, o); p3 += __shfl_xor(p3, o);
    }
    __shared__ float sm[4][4];
    if ((t & 63) == 0) { int w = t >> 6; sm[w][0] = p0; sm[w][1] = p1; sm[w][2] = p2; sm[w][3] = p3; }
    __syncthreads();
    if (t < 4) {
        float s = sm[0][t] + sm[1][t] + sm[2][t] + sm[3][t];
        rsinv[t * L_ + i] = 1.0f / s;
    }
}

// ---------------- MFMA GEMM core: C[128 x 64] tile, A[M,K] bf16, Bt[N,K] bf16 ----------------
__device__ __forceinline__ void mfma_tile_compute(const unsigned short* __restrict__ A,
                                                  const unsigned short* __restrict__ Bt,
                                                  int K, int m0, int n0,
                                                  unsigned short* sA, unsigned short* sB,
                                                  int t, floatx4 acc[4][2]) {
    const int lane = t & 63, wid = t >> 6;
    const int wm = (wid >> 1) * 64, wn = (wid & 1) * 32;
    const int lr = lane & 15, lq = lane >> 4;
    const int srow = t >> 2, sseg = (t & 3) * 8;
    const unsigned short* Ab0 = A + (size_t)(m0 + srow) * K + sseg;
    const unsigned short* Ab1 = A + (size_t)(m0 + srow + 64) * K + sseg;
    const unsigned short* Bb  = Bt + (size_t)(n0 + srow) * K + sseg;
    unsigned short* sAw0 = sA + srow * 40 + sseg;
    unsigned short* sAw1 = sA + (srow + 64) * 40 + sseg;
    unsigned short* sBw  = sB + srow * 40 + sseg;
    const unsigned short* sAr = sA + (wm + lr) * 40 + lq * 8;
    const unsigned short* sBr = sB + (wn + lr) * 40 + lq * 8;

    for (int k0 = 0; k0 < K; k0 += 32) {
        uint4 a0 = *(const uint4*)(Ab0 + k0);
        uint4 a1 = *(const uint4*)(Ab1 + k0);
        uint4 b0 = *(const uint4*)(Bb + k0);
        __syncthreads();
        *(uint4*)sAw0 = a0;
        *(uint4*)sAw1 = a1;
        *(uint4*)sBw  = b0;
        __syncthreads();
        bf16x8 af0 = *(const bf16x8*)(sAr);
        bf16x8 af1 = *(const bf16x8*)(sAr + 16 * 40);
        bf16x8 af2 = *(const bf16x8*)(sAr + 32 * 40);
        bf16x8 af3 = *(const bf16x8*)(sAr + 48 * 40);
        bf16x8 bf0 = *(const bf16x8*)(sBr);
        bf16x8 bf1 = *(const bf16x8*)(sBr + 16 * 40);
        acc[0][0] = __builtin_amdgcn_mfma_f32_16x16x32_bf16(af0, bf0, acc[0][0], 0, 0, 0);
        acc[0][1] = __builtin_amdgcn_mfma_f32_16x16x32_bf16(af0, bf1, acc[0][1], 0, 0, 0);
        acc[1][0] = __builtin_amdgcn_mfma_f32_16x16x32_bf16(af1, bf0, acc[1][0], 0, 0, 0);
        acc[1][1] = __builtin_amdgcn_mfma_f32_16x16x32_bf16(af1, bf1, acc[1][1], 0, 0, 0);
        acc[2][0] = __builtin_amdgcn_mfma_f32_16x16x32_bf16(af2, bf0, acc[2][0], 0, 0, 0);
        acc[2][1] = __builtin_amdgcn_mfma_f32_16x16x32_bf16(af2, bf1, acc[2][1], 0, 0, 0);
        acc[3][0] = __builtin_amdgcn_mfma_f32_16x16x32_bf16(af3, bf0, acc[3][0], 0, 0, 0);
        acc[3][1] = __builtin_amdgcn_mfma_f32_16x16x32_bf16(af3, bf1, acc[3][1], 0, 0, 0);
    }
}

#define MFMA_EPILOG_IDX \
    const int lane = threadIdx.x & 63, wid = threadIdx.x >> 6; \
    const int wm = (wid >> 1) * 64, wn = (wid & 1) * 32; \
    const int lr = lane & 15, lq = lane >> 4;

// ---------------- AV: C[2048,1024] = E @ XmT^T ----------------
__global__ __launch_bounds__(256) void k_av_mfma(const unsigned short* __restrict__ E,
                                                 const unsigned short* __restrict__ XmT,
                                                 float* __restrict__ C) {
    __shared__ unsigned short sA[128 * 40];
    __shared__ unsigned short sB[64 * 40];
    floatx4 acc[4][2];
#pragma unroll
    for (int i = 0; i < 4; i++)
#pragma unroll
        for (int j = 0; j < 2; j++) acc[i][j] = (floatx4){0.f, 0.f, 0.f, 0.f};
    int m0 = blockIdx.y * 128, n0 = blockIdx.x * 64;
    mfma_tile_compute(E, XmT, L_, m0, n0, sA, sB, threadIdx.x, acc);
    MFMA_EPILOG_IDX
#pragma unroll
    for (int i = 0; i < 4; i++)
#pragma unroll
        for (int j = 0; j < 2; j++)
#pragma unroll
            for (int r = 0; r < 4; r++) {
                int row = m0 + wm + i * 16 + lq * 4 + r;
                int col = n0 + wn + j * 16 + lr;
                C[(size_t)row * 1024 + col] = acc[i][j][r];
            }
}

// ---------------- LN1 fused: v = x + C/rs; LN -> h f32 + h bf16 ----------------
__global__ __launch_bounds__(256) void k_ln1(const float* __restrict__ x, const float* __restrict__ C,
                                             const float* __restrict__ rsinv,
                                             const float* __restrict__ g_, const float* __restrict__ be_,
                                             float* __restrict__ hf, unsigned short* __restrict__ hb) {
    int tok = blockIdx.x, t = threadIdx.x;
    int b = tok >> 11, i = tok & (L_ - 1);
    float v = x[(size_t)tok * D_ + t] + C[(size_t)i * 1024 + b * 256 + t] * rsinv[b * L_ + i];
    float s = v, s2 = v * v;
    __shared__ float sm[8];
#pragma unroll
    for (int o = 1; o < 64; o <<= 1) { s += __shfl_xor(s, o); s2 += __shfl_xor(s2, o); }
    if ((t & 63) == 0) { sm[t >> 6] = s; sm[4 + (t >> 6)] = s2; }
    __syncthreads();
    s = sm[0] + sm[1] + sm[2] + sm[3];
    s2 = sm[4] + sm[5] + sm[6] + sm[7];
    float mu = s * (1.f / 256.f);
    float var = s2 * (1.f / 256.f) - mu * mu;
    float r = rsqrtf(var + 1e-5f);
    float o = (v - mu) * r * g_[t] + be_[t];
    hf[(size_t)tok * D_ + t] = o;
    hb[(size_t)tok * D_ + t] = f2bf(o);
}

// ---------------- GEMM1: t1 = relu(h @ W1 + b1) bf16, M=8192 N=1024 K=256 ----------------
__global__ __launch_bounds__(256) void k_gemm1(const unsigned short* __restrict__ hb,
                                               const unsigned short* __restrict__ W1T,
                                               const float* __restrict__ b1, unsigned short* __restrict__ t1) {
    __shared__ unsigned short sA[128 * 40];
    __shared__ unsigned short sB[64 * 40];
    floatx4 acc[4][2];
#pragma unroll
    for (int i = 0; i < 4; i++)
#pragma unroll
        for (int j = 0; j < 2; j++) acc[i][j] = (floatx4){0.f, 0.f, 0.f, 0.f};
    int m0 = blockIdx.y * 128, n0 = blockIdx.x * 64;
    mfma_tile_compute(hb, W1T, 256, m0, n0, sA, sB, threadIdx.x, acc);
    MFMA_EPILOG_IDX
    float bb0 = b1[n0 + wn + lr], bb1 = b1[n0 + wn + 16 + lr];
#pragma unroll
    for (int i = 0; i < 4; i++)
#pragma unroll
        for (int j = 0; j < 2; j++) {
            float bv = j ? bb1 : bb0;
            int col = n0 + wn + j * 16 + lr;
#pragma unroll
            for (int r = 0; r < 4; r++) {
                int row = m0 + wm + i * 16 + lq * 4 + r;
                t1[(size_t)row * 1024 + col] = f2bf(fmaxf(acc[i][j][r] + bv, 0.f));
            }
        }
}

// ---------------- GEMM2: y2 = h + t1 @ W2 + b2, M=8192 N=256 K=1024 ----------------
__global__ __launch_bounds__(256) void k_gemm2(const unsigned short* __restrict__ t1,
                                               const unsigned short* __restrict__ W2T,
                                               const float* __restrict__ b2, const float* __restrict__ hf,
                                               float* __restrict__ y2) {
    __shared__ unsigned short sA[128 * 40];
    __shared__ unsigned short sB[64 * 40];
    floatx4 acc[4][2];
#pragma unroll
    for (int i = 0; i < 4; i++)
#pragma unroll
        for (int j = 0; j < 2; j++) acc[i][j] = (floatx4){0.f, 0.f, 0.f, 0.f};
    int m0 = blockIdx.y * 128, n0 = blockIdx.x * 64;
    mfma_tile_compute(t1, W2T, 1024, m0, n0, sA, sB, threadIdx.x, acc);
    MFMA_EPILOG_IDX
    float bb0 = b2[n0 + wn + lr], bb1 = b2[n0 + wn + 16 + lr];
#pragma unroll
    for (int i = 0; i < 4; i++)
#pragma unroll
        for (int j = 0; j < 2; j++) {
            float bv = j ? bb1 : bb0;
            int col = n0 + wn + j * 16 + lr;
#pragma unroll
            for (int r = 0; r < 4; r++) {
                int row = m0 + wm + i * 16 + lq * 4 + r;
                size_t idx = (size_t)row * 256 + col;
                y2[idx] = acc[i][j][r] + bv + hf[idx];
            }
        }
}

// ---------------- LN2 -> out f32 ----------------
__global__ __launch_bounds__(256) void k_ln2(const float* __restrict__ in,
                                             const float* __restrict__ g_, const float* __restrict__ be_,
                                             float* __restrict__ outf) {
    int tok = blockIdx.x, t = threadIdx.x;
    float v = in[(size_t)tok * D_ + t];
    float s = v, s2 = v * v;
    __shared__ float sm[8];
#pragma unroll
    for (int o = 1; o < 64; o <<= 1) { s += __shfl_xor(s, o); s2 += __shfl_xor(s2, o); }
    if ((t & 63) == 0) { sm[t >> 6] = s; sm[4 + (t >> 6)] = s2; }
    __syncthreads();
    s = sm[0] + sm[1] + sm[2] + sm[3];
    s2 = sm[4] + sm[5] + sm[6] + sm[7];
    float mu = s * (1.f / 256.f);
    float var = s2 * (1.f / 256.f) - mu * mu;
    float r = rsqrtf(var + 1e-5f);
    outf[(size_t)tok * D_ + t] = (v - mu) * r * g_[t] + be_[t];
}

extern "C" void kernel_launch(void* const* d_in, const int* in_sizes, int n_in,
                              void* d_out, int out_size, void* d_ws, size_t ws_size,
                              hipStream_t stream) {
    const float* x   = (const float*)d_in[0];
    const int*  mask = (const int*)d_in[1];
    const float* W1  = (const float*)d_in[2];
    const float* b1  = (const float*)d_in[3];
    const float* W2  = (const float*)d_in[4];
    const float* b2  = (const float*)d_in[5];
    const float* g1  = (const float*)d_in[6];
    const float* be1 = (const float*)d_in[7];
    const float* g2  = (const float*)d_in[8];
    const float* be2 = (const float*)d_in[9];
    float* out = (float*)d_out;

    char* w = (char*)d_ws;
    float*          m_    = (float*)w;                 w += 65536 * 4;          // 256 KB
    unsigned short* E_    = (unsigned short*)w;        w += (size_t)L_ * L_ * 2;    // 8 MB
    unsigned short* XmT_  = (unsigned short*)w;        w += (size_t)1024 * L_ * 2;  // 4 MB
    unsigned short* W1T_  = (unsigned short*)w;        w += 262144 * 2;         // 512 KB
    unsigned short* W2T_  = (unsigned short*)w;        w += 262144 * 2;         // 512 KB
    float*          rs_   = (float*)w;                 w += 8192 * 4;           // 32 KB
    float*          C_    = (float*)w;                 w += (size_t)L_ * 1024 * 4;  // 8 MB
    float*          hf_   = (float*)w;                 w += (size_t)8192 * 256 * 4; // 8 MB
    unsigned short* hb_   = (unsigned short*)w;        w += (size_t)8192 * 256 * 2; // 4 MB
    unsigned short* t1_   = (unsigned short*)w;        w += (size_t)8192 * 1024 * 2;// 16 MB
    float*          y2_   = (float*)w;                 w += (size_t)8192 * 256 * 4; // 8 MB

    k_mean<<<256, 256, 0, stream>>>(x, m_);
    k_scoresE<<<dim3(64, 64), 256, 0, stream>>>(m_, E_);
    k_transpose<<<dim3(32, 8, 1),  256, 0, stream>>>(W1, W1T_, 256, 1024, nullptr);
    k_transpose<<<dim3(8, 32, 1),  256, 0, stream>>>(W2, W2T_, 1024, 256, nullptr);
    k_transpose<<<dim3(8, 64, 4),  256, 0, stream>>>(x, XmT_, L_, 256, mask);
    k_rowsum<<<L_, 256, 0, stream>>>(E_, mask, rs_);
    k_av_mfma<<<dim3(16, 16), 256, 0, stream>>>(E_, XmT_, C_);
    k_ln1<<<B_ * L_, 256, 0, stream>>>(x, C_, rs_, g1, be1, hf_, hb_);
    k_gemm1<<<dim3(16, 64), 256, 0, stream>>>(hb_, W1T_, b1, t1_);
    k_gemm2<<<dim3(4, 64), 256, 0, stream>>>(t1_, W2T_, b2, hf_, y2_);
    k_ln2<<<B_ * L_, 256, 0, stream>>>(y2_, g2, be2, out);
}

// Round 5
// 169.268 us; speedup vs baseline: 3.5416x; 1.1142x over previous
//
#include <hip/hip_runtime.h>
#include <hip/hip_bf16.h>

// SelfAttentionTransformer: B=4, L=2048, D=256, H=8, dk=32, F=1024
// f32 inputs / f32 output. Round 5:
//  - scores dot-product via MFMA (m stored bf16), transcendental epilogue
//  - GEMM core: BK=64, global_load_lds(16B) staging, rotate-swizzled LDS
//    (seg' = (seg+row)&7) -> ds_read_b128 with <=2-way conflicts (free)
//  - residual for GEMM2 taken from bf16 h (drops hf_ buffer)

#define B_ 4
#define L_ 2048
#define D_ 256
#define F_ 1024
#define PI_F 3.14159265358979323846f

typedef __bf16 bf16x8 __attribute__((ext_vector_type(8)));
typedef float floatx4 __attribute__((ext_vector_type(4)));

__device__ __forceinline__ unsigned short f2bf(float f) {
    unsigned int u = __float_as_uint(f);
    u = (u + 0x7FFFu + ((u >> 16) & 1u)) >> 16;   // RNE
    return (unsigned short)u;
}
__device__ __forceinline__ float bf2f(unsigned short u) {
    union { unsigned int i; float f; } v; v.i = ((unsigned int)u) << 16; return v.f;
}

__device__ __forceinline__ void async_cp16(unsigned short* lds, const unsigned short* g) {
    __builtin_amdgcn_global_load_lds(
        (const __attribute__((address_space(1))) unsigned int*)g,
        (__attribute__((address_space(3))) unsigned int*)lds, 16, 0, 0);
}

// ---------------- m = mean over (b,h) of xh : [L, 32], bf16 out ----------------
__global__ __launch_bounds__(256) void k_mean(const float* __restrict__ x, unsigned short* __restrict__ mb) {
    int idx = blockIdx.x * 256 + threadIdx.x;   // L*32 = 65536
    int l = idx >> 5, k = idx & 31;
    float s = 0.f;
#pragma unroll
    for (int b = 0; b < B_; b++) {
        const float* xp = x + ((size_t)(b * L_ + l)) * D_ + k;
#pragma unroll
        for (int h = 0; h < 8; h++) s += xp[h * 32];
    }
    mb[idx] = f2bf(s * (1.f / 32.f));
}

// ---------------- E = exp(sin^2(0.5*clip(m.mT))) via MFMA, bf16 out ----------------
// grid (L/64, L/128); block 128x64 tile; K=32 (one mfma per 16x16 pair)
__global__ __launch_bounds__(256) void k_scores_mfma(const unsigned short* __restrict__ mb,
                                                     unsigned short* __restrict__ E) {
    const int t = threadIdx.x, lane = t & 63, wid = t >> 6;
    const int wm = (wid >> 1) * 64, wn = (wid & 1) * 32;
    const int lr = lane & 15, lq = lane >> 4;
    int m0 = blockIdx.y * 128, n0 = blockIdx.x * 64;
    bf16x8 af[4], bfr[2];
#pragma unroll
    for (int i = 0; i < 4; i++)
        af[i] = *(const bf16x8*)(mb + (size_t)(m0 + wm + i * 16 + lr) * 32 + lq * 8);
#pragma unroll
    for (int j = 0; j < 2; j++)
        bfr[j] = *(const bf16x8*)(mb + (size_t)(n0 + wn + j * 16 + lr) * 32 + lq * 8);
    floatx4 acc[4][2];
#pragma unroll
    for (int i = 0; i < 4; i++)
#pragma unroll
        for (int j = 0; j < 2; j++) {
            acc[i][j] = (floatx4){0.f, 0.f, 0.f, 0.f};
            acc[i][j] = __builtin_amdgcn_mfma_f32_16x16x32_bf16(af[i], bfr[j], acc[i][j], 0, 0, 0);
        }
#pragma unroll
    for (int i = 0; i < 4; i++)
#pragma unroll
        for (int j = 0; j < 2; j++)
#pragma unroll
            for (int r = 0; r < 4; r++) {
                int row = m0 + wm + i * 16 + lq * 4 + r;
                int col = n0 + wn + j * 16 + lr;
                float d = fminf(fmaxf(acc[i][j][r], -PI_F), PI_F);
                float sn = __sinf(0.5f * d);
                E[(size_t)row * L_ + col] = f2bf(__expf(sn * sn));
            }
}

// ---------------- generic f32 [R,C] -> bf16 [C,R] transpose, optional row-mask ----------------
__global__ __launch_bounds__(256) void k_transpose(const float* __restrict__ in, unsigned short* __restrict__ out,
                                                   int R, int C, const int* __restrict__ mask) {
    __shared__ float tile[32][33];
    int r0 = blockIdx.y * 32, c0 = blockIdx.x * 32;
    size_t bo = (size_t)blockIdx.z * R * C;
    int t = threadIdx.x, tx = t & 31, ty = t >> 5;
#pragma unroll
    for (int rr = 0; rr < 4; rr++) {
        int r = ty + rr * 8;
        tile[r][tx] = in[bo + (size_t)(r0 + r) * C + c0 + tx];
    }
    float mfac = 1.f;
    if (mask) mfac = mask[(size_t)blockIdx.z * R + r0 + tx] ? 1.f : 0.f;
    __syncthreads();
#pragma unroll
    for (int rr = 0; rr < 4; rr++) {
        int c = ty + rr * 8;
        out[bo + (size_t)(c0 + c) * R + r0 + tx] = f2bf(tile[tx][c] * mfac);
    }
}

// ---------------- rsinv[b,i] = 1 / sum_j mask[b,j]*E[i,j] ----------------
__global__ __launch_bounds__(256) void k_rowsum(const unsigned short* __restrict__ E, const int* __restrict__ mask,
                                                float* __restrict__ rsinv) {
    int i = blockIdx.x, t = threadIdx.x;
    float p0 = 0.f, p1 = 0.f, p2 = 0.f, p3 = 0.f;
#pragma unroll
    for (int c = 0; c < 8; c++) {
        int j = t + c * 256;
        float e = bf2f(E[(size_t)i * L_ + j]);
        if (mask[j]) p0 += e;
        if (mask[L_ + j]) p1 += e;
        if (mask[2 * L_ + j]) p2 += e;
        if (mask[3 * L_ + j]) p3 += e;
    }
#pragma unroll
    for (int o = 1; o < 64; o <<= 1) {
        p0 += __shfl_xor(p0, o); p1 += __shfl_xor(p1, o);
        p2 += __shfl_xor(p2, o); p3 += __shfl_xor(p3, o);
    }
    __shared__ float sm[4][4];
    if ((t & 63) == 0) { int w = t >> 6; sm[w][0] = p0; sm[w][1] = p1; sm[w][2] = p2; sm[w][3] = p3; }
    __syncthreads();
    if (t < 4) {
        float s = sm[0][t] + sm[1][t] + sm[2][t] + sm[3][t];
        rsinv[t * L_ + i] = 1.0f / s;
    }
}

// ---------------- MFMA GEMM core: BM=128 BN=64 BK=64, async staging + swizzle ----------------
// A[M,K] bf16, Bt[N,K] bf16. LDS rows: 64 elems (128B) = 8 segs of 16B,
// stored rotated: seg' = (seg + local_row) & 7.
__device__ __forceinline__ void mfma_gemm_async(const unsigned short* __restrict__ A,
                                                const unsigned short* __restrict__ Bt,
                                                int K, int m0, int n0,
                                                unsigned short* sA, unsigned short* sB,
                                                floatx4 acc[4][2]) {
    const int t = threadIdx.x;
    const int lane = t & 63, wid = t >> 6;
    const int wm = (wid >> 1) * 64, wn = (wid & 1) * 32;
    const int lr = lane & 15, lq = lane >> 4;
    const int lrow = lane >> 3, lseg = lane & 7;

    const unsigned short* Ag[4]; unsigned short* sAd[4];
#pragma unroll
    for (int q = 0; q < 4; q++) {
        int rl = wid * 32 + q * 8 + lrow;
        int seg = (lseg - rl) & 7;
        Ag[q] = A + (size_t)(m0 + rl) * K + seg * 8;
        sAd[q] = sA + (wid * 32 + q * 8) * 64;
    }
    const unsigned short* Bg[2]; unsigned short* sBd[2];
#pragma unroll
    for (int q = 0; q < 2; q++) {
        int rl = wid * 16 + q * 8 + lrow;
        int seg = (lseg - rl) & 7;
        Bg[q] = Bt + (size_t)(n0 + rl) * K + seg * 8;
        sBd[q] = sB + (wid * 16 + q * 8) * 64;
    }
    int arot[4], brot[2];
    const unsigned short* sAr[4]; const unsigned short* sBr[2];
#pragma unroll
    for (int i = 0; i < 4; i++) { int ar = wm + i * 16 + lr; sAr[i] = sA + ar * 64; arot[i] = lq + ar; }
#pragma unroll
    for (int j = 0; j < 2; j++) { int br = wn + j * 16 + lr; sBr[j] = sB + br * 64; brot[j] = lq + br; }

    for (int k0 = 0; k0 < K; k0 += 64) {
        __syncthreads();
#pragma unroll
        for (int q = 0; q < 4; q++) async_cp16(sAd[q], Ag[q] + k0);
#pragma unroll
        for (int q = 0; q < 2; q++) async_cp16(sBd[q], Bg[q] + k0);
        __syncthreads();
#pragma unroll
        for (int s = 0; s < 2; s++) {
            bf16x8 af[4], bfr[2];
#pragma unroll
            for (int i = 0; i < 4; i++)
                af[i] = *(const bf16x8*)(sAr[i] + ((s * 4 + arot[i]) & 7) * 8);
#pragma unroll
            for (int j = 0; j < 2; j++)
                bfr[j] = *(const bf16x8*)(sBr[j] + ((s * 4 + brot[j]) & 7) * 8);
#pragma unroll
            for (int i = 0; i < 4; i++)
#pragma unroll
                for (int j = 0; j < 2; j++)
                    acc[i][j] = __builtin_amdgcn_mfma_f32_16x16x32_bf16(af[i], bfr[j], acc[i][j], 0, 0, 0);
        }
    }
}

#define MFMA_EPILOG_IDX \
    const int lane = threadIdx.x & 63, wid = threadIdx.x >> 6; \
    const int wm = (wid >> 1) * 64, wn = (wid & 1) * 32; \
    const int lr = lane & 15, lq = lane >> 4;

// ---------------- AV: C[2048,1024] = E @ XmT^T (f32 out) ----------------
__global__ __launch_bounds__(256) void k_av(const unsigned short* __restrict__ E,
                                            const unsigned short* __restrict__ XmT,
                                            float* __restrict__ C) {
    __shared__ __align__(16) unsigned short sA[128 * 64];
    __shared__ __align__(16) unsigned short sB[64 * 64];
    floatx4 acc[4][2];
#pragma unroll
    for (int i = 0; i < 4; i++)
#pragma unroll
        for (int j = 0; j < 2; j++) acc[i][j] = (floatx4){0.f, 0.f, 0.f, 0.f};
    int m0 = blockIdx.y * 128, n0 = blockIdx.x * 64;
    mfma_gemm_async(E, XmT, L_, m0, n0, sA, sB, acc);
    MFMA_EPILOG_IDX
#pragma unroll
    for (int i = 0; i < 4; i++)
#pragma unroll
        for (int j = 0; j < 2; j++)
#pragma unroll
            for (int r = 0; r < 4; r++) {
                int row = m0 + wm + i * 16 + lq * 4 + r;
                int col = n0 + wn + j * 16 + lr;
                C[(size_t)row * 1024 + col] = acc[i][j][r];
            }
}

// ---------------- LN1 fused: v = x + C*rsinv; LN -> h bf16 ----------------
__global__ __launch_bounds__(256) void k_ln1(const float* __restrict__ x, const float* __restrict__ C,
                                             const float* __restrict__ rsinv,
                                             const float* __restrict__ g_, const float* __restrict__ be_,
                                             unsigned short* __restrict__ hb) {
    int tok = blockIdx.x, t = threadIdx.x;
    int b = tok >> 11, i = tok & (L_ - 1);
    float v = x[(size_t)tok * D_ + t] + C[(size_t)i * 1024 + b * 256 + t] * rsinv[b * L_ + i];
    float s = v, s2 = v * v;
    __shared__ float sm[8];
#pragma unroll
    for (int o = 1; o < 64; o <<= 1) { s += __shfl_xor(s, o); s2 += __shfl_xor(s2, o); }
    if ((t & 63) == 0) { sm[t >> 6] = s; sm[4 + (t >> 6)] = s2; }
    __syncthreads();
    s = sm[0] + sm[1] + sm[2] + sm[3];
    s2 = sm[4] + sm[5] + sm[6] + sm[7];
    float mu = s * (1.f / 256.f);
    float var = s2 * (1.f / 256.f) - mu * mu;
    float r = rsqrtf(var + 1e-5f);
    hb[(size_t)tok * D_ + t] = f2bf((v - mu) * r * g_[t] + be_[t]);
}

// ---------------- GEMM1: t1 = relu(h @ W1 + b1) bf16 ----------------
__global__ __launch_bounds__(256) void k_gemm1(const unsigned short* __restrict__ hb,
                                               const unsigned short* __restrict__ W1T,
                                               const float* __restrict__ b1, unsigned short* __restrict__ t1) {
    __shared__ __align__(16) unsigned short sA[128 * 64];
    __shared__ __align__(16) unsigned short sB[64 * 64];
    floatx4 acc[4][2];
#pragma unroll
    for (int i = 0; i < 4; i++)
#pragma unroll
        for (int j = 0; j < 2; j++) acc[i][j] = (floatx4){0.f, 0.f, 0.f, 0.f};
    int m0 = blockIdx.y * 128, n0 = blockIdx.x * 64;
    mfma_gemm_async(hb, W1T, 256, m0, n0, sA, sB, acc);
    MFMA_EPILOG_IDX
    float bb0 = b1[n0 + wn + lr], bb1 = b1[n0 + wn + 16 + lr];
#pragma unroll
    for (int i = 0; i < 4; i++)
#pragma unroll
        for (int j = 0; j < 2; j++) {
            float bv = j ? bb1 : bb0;
            int col = n0 + wn + j * 16 + lr;
#pragma unroll
            for (int r = 0; r < 4; r++) {
                int row = m0 + wm + i * 16 + lq * 4 + r;
                t1[(size_t)row * 1024 + col] = f2bf(fmaxf(acc[i][j][r] + bv, 0.f));
            }
        }
}

// ---------------- GEMM2: y2 = h + t1 @ W2 + b2 (f32 out) ----------------
__global__ __launch_bounds__(256) void k_gemm2(const unsigned short* __restrict__ t1,
                                               const unsigned short* __restrict__ W2T,
                                               const float* __restrict__ b2, const unsigned short* __restrict__ hb,
                                               float* __restrict__ y2) {
    __shared__ __align__(16) unsigned short sA[128 * 64];
    __shared__ __align__(16) unsigned short sB[64 * 64];
    floatx4 acc[4][2];
#pragma unroll
    for (int i = 0; i < 4; i++)
#pragma unroll
        for (int j = 0; j < 2; j++) acc[i][j] = (floatx4){0.f, 0.f, 0.f, 0.f};
    int m0 = blockIdx.y * 128, n0 = blockIdx.x * 64;
    mfma_gemm_async(t1, W2T, 1024, m0, n0, sA, sB, acc);
    MFMA_EPILOG_IDX
    float bb0 = b2[n0 + wn + lr], bb1 = b2[n0 + wn + 16 + lr];
#pragma unroll
    for (int i = 0; i < 4; i++)
#pragma unroll
        for (int j = 0; j < 2; j++) {
            float bv = j ? bb1 : bb0;
            int col = n0 + wn + j * 16 + lr;
#pragma unroll
            for (int r = 0; r < 4; r++) {
                int row = m0 + wm + i * 16 + lq * 4 + r;
                size_t idx = (size_t)row * 256 + col;
                y2[idx] = acc[i][j][r] + bv + bf2f(hb[idx]);
            }
        }
}

// ---------------- LN2 -> out f32 ----------------
__global__ __launch_bounds__(256) void k_ln2(const float* __restrict__ in,
                                             const float* __restrict__ g_, const float* __restrict__ be_,
                                             float* __restrict__ outf) {
    int tok = blockIdx.x, t = threadIdx.x;
    float v = in[(size_t)tok * D_ + t];
    float s = v, s2 = v * v;
    __shared__ float sm[8];
#pragma unroll
    for (int o = 1; o < 64; o <<= 1) { s += __shfl_xor(s, o); s2 += __shfl_xor(s2, o); }
    if ((t & 63) == 0) { sm[t >> 6] = s; sm[4 + (t >> 6)] = s2; }
    __syncthreads();
    s = sm[0] + sm[1] + sm[2] + sm[3];
    s2 = sm[4] + sm[5] + sm[6] + sm[7];
    float mu = s * (1.f / 256.f);
    float var = s2 * (1.f / 256.f) - mu * mu;
    float r = rsqrtf(var + 1e-5f);
    outf[(size_t)tok * D_ + t] = (v - mu) * r * g_[t] + be_[t];
}

extern "C" void kernel_launch(void* const* d_in, const int* in_sizes, int n_in,
                              void* d_out, int out_size, void* d_ws, size_t ws_size,
                              hipStream_t stream) {
    const float* x   = (const float*)d_in[0];
    const int*  mask = (const int*)d_in[1];
    const float* W1  = (const float*)d_in[2];
    const float* b1  = (const float*)d_in[3];
    const float* W2  = (const float*)d_in[4];
    const float* b2  = (const float*)d_in[5];
    const float* g1  = (const float*)d_in[6];
    const float* be1 = (const float*)d_in[7];
    const float* g2  = (const float*)d_in[8];
    const float* be2 = (const float*)d_in[9];
    float* out = (float*)d_out;

    char* w = (char*)d_ws;
    unsigned short* mb_   = (unsigned short*)w;        w += 65536 * 2;               // 128 KB
    unsigned short* E_    = (unsigned short*)w;        w += (size_t)L_ * L_ * 2;     // 8 MB
    unsigned short* XmT_  = (unsigned short*)w;        w += (size_t)1024 * L_ * 2;   // 4 MB
    unsigned short* W1T_  = (unsigned short*)w;        w += 262144 * 2;              // 512 KB
    unsigned short* W2T_  = (unsigned short*)w;        w += 262144 * 2;              // 512 KB
    float*          rs_   = (float*)w;                 w += 8192 * 4;                // 32 KB
    float*          C_    = (float*)w;                 w += (size_t)L_ * 1024 * 4;   // 8 MB
    unsigned short* hb_   = (unsigned short*)w;        w += (size_t)8192 * 256 * 2;  // 4 MB
    unsigned short* t1_   = (unsigned short*)w;        w += (size_t)8192 * 1024 * 2; // 16 MB
    float*          y2_   = (float*)w;                 w += (size_t)8192 * 256 * 4;  // 8 MB

    k_mean<<<256, 256, 0, stream>>>(x, mb_);
    k_scores_mfma<<<dim3(32, 16), 256, 0, stream>>>(mb_, E_);
    k_transpose<<<dim3(32, 8, 1),  256, 0, stream>>>(W1, W1T_, 256, 1024, nullptr);
    k_transpose<<<dim3(8, 32, 1),  256, 0, stream>>>(W2, W2T_, 1024, 256, nullptr);
    k_transpose<<<dim3(8, 64, 4),  256, 0, stream>>>(x, XmT_, L_, 256, mask);
    k_rowsum<<<L_, 256, 0, stream>>>(E_, mask, rs_);
    k_av<<<dim3(16, 16), 256, 0, stream>>>(E_, XmT_, C_);
    k_ln1<<<B_ * L_, 256, 0, stream>>>(x, C_, rs_, g1, be1, hb_);
    k_gemm1<<<dim3(16, 64), 256, 0, stream>>>(hb_, W1T_, b1, t1_);
    k_gemm2<<<dim3(4, 64), 256, 0, stream>>>(t1_, W2T_, b2, hb_, y2_);
    k_ln2<<<B_ * L_, 256, 0, stream>>>(y2_, g2, be2, out);
}

// Round 6
// 153.367 us; speedup vs baseline: 3.9088x; 1.1037x over previous
//
#include <hip/hip_runtime.h>
#include <hip/hip_bf16.h>

// SelfAttentionTransformer: B=4, L=2048, D=256, H=8, dk=32, F=1024
// f32 inputs / f32 output. Round 6: 6 kernels (was 11).
//  - k_prep: mean + W1/W2/x transposes + mask-rows appended to XmT (z-mux)
//  - rowsum folded into AV GEMM: XmT rows 1024..1027 = mask[b,:] (bf16) ->
//    C[:,1024+b] = sum_j E[i,j]*mask[b,j]  (free with the MFMA GEMM)
//  - k_av re-tiled to 64x64, grid 544 (>=2 blocks/CU)
//  - LN2 fused into GEMM2 (32x256 full-row tile, cross-wave LDS reduce)

#define B_ 4
#define L_ 2048
#define D_ 256
#define F_ 1024
#define PI_F 3.14159265358979323846f

typedef __bf16 bf16x8 __attribute__((ext_vector_type(8)));
typedef float floatx4 __attribute__((ext_vector_type(4)));

__device__ __forceinline__ unsigned short f2bf(float f) {
    unsigned int u = __float_as_uint(f);
    u = (u + 0x7FFFu + ((u >> 16) & 1u)) >> 16;   // RNE
    return (unsigned short)u;
}
__device__ __forceinline__ float bf2f(unsigned short u) {
    union { unsigned int i; float f; } v; v.i = ((unsigned int)u) << 16; return v.f;
}

__device__ __forceinline__ void async_cp16(unsigned short* lds, const unsigned short* g) {
    __builtin_amdgcn_global_load_lds(
        (const __attribute__((address_space(1))) unsigned int*)g,
        (__attribute__((address_space(3))) unsigned int*)lds, 16, 0, 0);
}

// ---------------- prep multiplex: z=0..3 x-transpose(masked), z=4 W1T, z=5 W2T,
// z=6 mean->bf16, z=7 mask rows of XmT ----------------
__global__ __launch_bounds__(256) void k_prep(const float* __restrict__ x,
                                              const float* __restrict__ W1,
                                              const float* __restrict__ W2,
                                              const int* __restrict__ mask,
                                              unsigned short* __restrict__ mb,
                                              unsigned short* __restrict__ XmT,
                                              unsigned short* __restrict__ W1T,
                                              unsigned short* __restrict__ W2T) {
    int z = blockIdx.z, t = threadIdx.x;
    if (z == 6) {
        if (blockIdx.x >= 4) return;
        int idx = (blockIdx.y * 4 + blockIdx.x) * 256 + t;   // 0..65535
        int l = idx >> 5, k = idx & 31;
        float s = 0.f;
#pragma unroll
        for (int b = 0; b < B_; b++) {
            const float* xp = x + ((size_t)(b * L_ + l)) * D_ + k;
#pragma unroll
            for (int h = 0; h < 8; h++) s += xp[h * 32];
        }
        mb[idx] = f2bf(s * (1.f / 32.f));
        return;
    }
    if (z == 7) {
        if (blockIdx.x || blockIdx.y) return;
#pragma unroll
        for (int c = 0; c < 32; c++) {
            int e = c * 256 + t;            // 0..8191
            int b = e >> 11, j = e & (L_ - 1);
            XmT[(size_t)(1024 + b) * L_ + j] = mask[b * L_ + j] ? 0x3F80 : 0;
        }
        return;
    }
    const float* in; unsigned short* outp; int R, C; const int* mrow = nullptr; size_t bo = 0;
    if (z < 4) {
        if (blockIdx.x >= 8) return;
        in = x; outp = XmT; R = L_; C = 256; bo = (size_t)z * R * C; mrow = mask + z * L_;
    } else if (z == 4) {
        if (blockIdx.y >= 8) return;
        in = W1; outp = W1T; R = 256; C = 1024;
    } else {
        if (blockIdx.x >= 8 || blockIdx.y >= 32) return;
        in = W2; outp = W2T; R = 1024; C = 256;
    }
    __shared__ float tile[32][33];
    int r0 = blockIdx.y * 32, c0 = blockIdx.x * 32;
    int tx = t & 31, ty = t >> 5;
#pragma unroll
    for (int rr = 0; rr < 4; rr++) {
        int r = ty + rr * 8;
        tile[r][tx] = in[bo + (size_t)(r0 + r) * C + c0 + tx];
    }
    float mfac = 1.f;
    if (mrow) mfac = mrow[r0 + tx] ? 1.f : 0.f;
    __syncthreads();
#pragma unroll
    for (int rr = 0; rr < 4; rr++) {
        int c = ty + rr * 8;
        outp[bo + (size_t)(c0 + c) * R + r0 + tx] = f2bf(tile[tx][c] * mfac);
    }
}

// ---------------- E = exp(sin^2(0.5*clip(m.mT))) via MFMA, bf16 out ----------------
__global__ __launch_bounds__(256) void k_scores_mfma(const unsigned short* __restrict__ mb,
                                                     unsigned short* __restrict__ E) {
    const int t = threadIdx.x, lane = t & 63, wid = t >> 6;
    const int wm = (wid >> 1) * 64, wn = (wid & 1) * 32;
    const int lr = lane & 15, lq = lane >> 4;
    int m0 = blockIdx.y * 128, n0 = blockIdx.x * 64;
    bf16x8 af[4], bfr[2];
#pragma unroll
    for (int i = 0; i < 4; i++)
        af[i] = *(const bf16x8*)(mb + (size_t)(m0 + wm + i * 16 + lr) * 32 + lq * 8);
#pragma unroll
    for (int j = 0; j < 2; j++)
        bfr[j] = *(const bf16x8*)(mb + (size_t)(n0 + wn + j * 16 + lr) * 32 + lq * 8);
    floatx4 acc[4][2];
#pragma unroll
    for (int i = 0; i < 4; i++)
#pragma unroll
        for (int j = 0; j < 2; j++) {
            acc[i][j] = (floatx4){0.f, 0.f, 0.f, 0.f};
            acc[i][j] = __builtin_amdgcn_mfma_f32_16x16x32_bf16(af[i], bfr[j], acc[i][j], 0, 0, 0);
        }
#pragma unroll
    for (int i = 0; i < 4; i++)
#pragma unroll
        for (int j = 0; j < 2; j++)
#pragma unroll
            for (int r = 0; r < 4; r++) {
                int row = m0 + wm + i * 16 + lq * 4 + r;
                int col = n0 + wn + j * 16 + lr;
                float d = fminf(fmaxf(acc[i][j][r], -PI_F), PI_F);
                float sn = __sinf(0.5f * d);
                E[(size_t)row * L_ + col] = f2bf(__expf(sn * sn));
            }
}

// ---------------- AV: C[2048,1088] = E @ XmT^T (64x64 tiles, grid (17,32)) ----------------
__global__ __launch_bounds__(256) void k_av(const unsigned short* __restrict__ E,
                                            const unsigned short* __restrict__ XmT,
                                            float* __restrict__ C) {
    __shared__ __align__(16) unsigned short sA[64 * 64];
    __shared__ __align__(16) unsigned short sB[64 * 64];
    const int t = threadIdx.x, lane = t & 63, wid = t >> 6;
    const int wm = (wid >> 1) * 32, wn = (wid & 1) * 32;
    const int lr = lane & 15, lq = lane >> 4;
    const int lrow8 = lane >> 3, lseg = lane & 7;
    int m0 = blockIdx.y * 64, n0 = blockIdx.x * 64;

    const unsigned short* Ag[2]; unsigned short* sAd[2];
    const unsigned short* Bg[2]; unsigned short* sBd[2];
#pragma unroll
    for (int q = 0; q < 2; q++) {
        int rl = q * 32 + wid * 8 + lrow8;
        int seg = (lseg - rl) & 7;
        Ag[q] = E + (size_t)(m0 + rl) * L_ + seg * 8;
        Bg[q] = XmT + (size_t)(n0 + rl) * L_ + seg * 8;
        sAd[q] = sA + (q * 32 + wid * 8) * 64;
        sBd[q] = sB + (q * 32 + wid * 8) * 64;
    }
    const unsigned short* sAr[2]; int arot[2];
    const unsigned short* sBr[2]; int brot[2];
#pragma unroll
    for (int i = 0; i < 2; i++) { int ar = wm + i * 16 + lr; sAr[i] = sA + ar * 64; arot[i] = lq + ar; }
#pragma unroll
    for (int j = 0; j < 2; j++) { int br = wn + j * 16 + lr; sBr[j] = sB + br * 64; brot[j] = lq + br; }

    floatx4 acc[2][2];
#pragma unroll
    for (int i = 0; i < 2; i++)
#pragma unroll
        for (int j = 0; j < 2; j++) acc[i][j] = (floatx4){0.f, 0.f, 0.f, 0.f};

    for (int k0 = 0; k0 < L_; k0 += 64) {
        __syncthreads();
#pragma unroll
        for (int q = 0; q < 2; q++) { async_cp16(sAd[q], Ag[q] + k0); async_cp16(sBd[q], Bg[q] + k0); }
        __syncthreads();
#pragma unroll
        for (int s = 0; s < 2; s++) {
            bf16x8 af[2], bfr[2];
#pragma unroll
            for (int i = 0; i < 2; i++) af[i] = *(const bf16x8*)(sAr[i] + ((s * 4 + arot[i]) & 7) * 8);
#pragma unroll
            for (int j = 0; j < 2; j++) bfr[j] = *(const bf16x8*)(sBr[j] + ((s * 4 + brot[j]) & 7) * 8);
#pragma unroll
            for (int i = 0; i < 2; i++)
#pragma unroll
                for (int j = 0; j < 2; j++)
                    acc[i][j] = __builtin_amdgcn_mfma_f32_16x16x32_bf16(af[i], bfr[j], acc[i][j], 0, 0, 0);
        }
    }
#pragma unroll
    for (int i = 0; i < 2; i++)
#pragma unroll
        for (int j = 0; j < 2; j++)
#pragma unroll
            for (int r = 0; r < 4; r++) {
                int row = m0 + wm + i * 16 + lq * 4 + r;
                int col = n0 + wn + j * 16 + lr;
                C[(size_t)row * 1088 + col] = acc[i][j][r];
            }
}

// ---------------- LN1 fused: v = x + C/rs; LN -> h bf16 ----------------
__global__ __launch_bounds__(256) void k_ln1(const float* __restrict__ x, const float* __restrict__ C,
                                             const float* __restrict__ g_, const float* __restrict__ be_,
                                             unsigned short* __restrict__ hb) {
    int tok = blockIdx.x, t = threadIdx.x;
    int b = tok >> 11, i = tok & (L_ - 1);
    float rs = C[(size_t)i * 1088 + 1024 + b];
    float v = x[(size_t)tok * D_ + t] + C[(size_t)i * 1088 + b * 256 + t] / rs;
    float s = v, s2 = v * v;
    __shared__ float sm[8];
#pragma unroll
    for (int o = 1; o < 64; o <<= 1) { s += __shfl_xor(s, o); s2 += __shfl_xor(s2, o); }
    if ((t & 63) == 0) { sm[t >> 6] = s; sm[4 + (t >> 6)] = s2; }
    __syncthreads();
    s = sm[0] + sm[1] + sm[2] + sm[3];
    s2 = sm[4] + sm[5] + sm[6] + sm[7];
    float mu = s * (1.f / 256.f);
    float var = s2 * (1.f / 256.f) - mu * mu;
    float r = rsqrtf(var + 1e-5f);
    hb[(size_t)tok * D_ + t] = f2bf((v - mu) * r * g_[t] + be_[t]);
}

// ---------------- GEMM core 128x64 (round-5, validated): used by GEMM1 ----------------
__device__ __forceinline__ void mfma_gemm_async(const unsigned short* __restrict__ A,
                                                const unsigned short* __restrict__ Bt,
                                                int K, int m0, int n0,
                                                unsigned short* sA, unsigned short* sB,
                                                floatx4 acc[4][2]) {
    const int t = threadIdx.x;
    const int lane = t & 63, wid = t >> 6;
    const int wm = (wid >> 1) * 64, wn = (wid & 1) * 32;
    const int lr = lane & 15, lq = lane >> 4;
    const int lrow = lane >> 3, lseg = lane & 7;

    const unsigned short* Ag[4]; unsigned short* sAd[4];
#pragma unroll
    for (int q = 0; q < 4; q++) {
        int rl = wid * 32 + q * 8 + lrow;
        int seg = (lseg - rl) & 7;
        Ag[q] = A + (size_t)(m0 + rl) * K + seg * 8;
        sAd[q] = sA + (wid * 32 + q * 8) * 64;
    }
    const unsigned short* Bg[2]; unsigned short* sBd[2];
#pragma unroll
    for (int q = 0; q < 2; q++) {
        int rl = wid * 16 + q * 8 + lrow;
        int seg = (lseg - rl) & 7;
        Bg[q] = Bt + (size_t)(n0 + rl) * K + seg * 8;
        sBd[q] = sB + (wid * 16 + q * 8) * 64;
    }
    int arot[4], brot[2];
    const unsigned short* sAr[4]; const unsigned short* sBr[2];
#pragma unroll
    for (int i = 0; i < 4; i++) { int ar = wm + i * 16 + lr; sAr[i] = sA + ar * 64; arot[i] = lq + ar; }
#pragma unroll
    for (int j = 0; j < 2; j++) { int br = wn + j * 16 + lr; sBr[j] = sB + br * 64; brot[j] = lq + br; }

    for (int k0 = 0; k0 < K; k0 += 64) {
        __syncthreads();
#pragma unroll
        for (int q = 0; q < 4; q++) async_cp16(sAd[q], Ag[q] + k0);
#pragma unroll
        for (int q = 0; q < 2; q++) async_cp16(sBd[q], Bg[q] + k0);
        __syncthreads();
#pragma unroll
        for (int s = 0; s < 2; s++) {
            bf16x8 af[4], bfr[2];
#pragma unroll
            for (int i = 0; i < 4; i++)
                af[i] = *(const bf16x8*)(sAr[i] + ((s * 4 + arot[i]) & 7) * 8);
#pragma unroll
            for (int j = 0; j < 2; j++)
                bfr[j] = *(const bf16x8*)(sBr[j] + ((s * 4 + brot[j]) & 7) * 8);
#pragma unroll
            for (int i = 0; i < 4; i++)
#pragma unroll
                for (int j = 0; j < 2; j++)
                    acc[i][j] = __builtin_amdgcn_mfma_f32_16x16x32_bf16(af[i], bfr[j], acc[i][j], 0, 0, 0);
        }
    }
}

// ---------------- GEMM1: t1 = relu(h @ W1 + b1) bf16 ----------------
__global__ __launch_bounds__(256) void k_gemm1(const unsigned short* __restrict__ hb,
                                               const unsigned short* __restrict__ W1T,
                                               const float* __restrict__ b1, unsigned short* __restrict__ t1) {
    __shared__ __align__(16) unsigned short sA[128 * 64];
    __shared__ __align__(16) unsigned short sB[64 * 64];
    floatx4 acc[4][2];
#pragma unroll
    for (int i = 0; i < 4; i++)
#pragma unroll
        for (int j = 0; j < 2; j++) acc[i][j] = (floatx4){0.f, 0.f, 0.f, 0.f};
    int m0 = blockIdx.y * 128, n0 = blockIdx.x * 64;
    mfma_gemm_async(hb, W1T, 256, m0, n0, sA, sB, acc);
    const int lane = threadIdx.x & 63, wid = threadIdx.x >> 6;
    const int wm = (wid >> 1) * 64, wn = (wid & 1) * 32;
    const int lr = lane & 15, lq = lane >> 4;
    float bb0 = b1[n0 + wn + lr], bb1 = b1[n0 + wn + 16 + lr];
#pragma unroll
    for (int i = 0; i < 4; i++)
#pragma unroll
        for (int j = 0; j < 2; j++) {
            float bv = j ? bb1 : bb0;
            int col = n0 + wn + j * 16 + lr;
#pragma unroll
            for (int r = 0; r < 4; r++) {
                int row = m0 + wm + i * 16 + lq * 4 + r;
                t1[(size_t)row * 1024 + col] = f2bf(fmaxf(acc[i][j][r] + bv, 0.f));
            }
        }
}

// ---------------- GEMM2+LN2 fused: out = LN(h + t1 @ W2 + b2), tile 32 x 256 ----------------
__global__ __launch_bounds__(256) void k_gemm2ln(const unsigned short* __restrict__ t1,
                                                 const unsigned short* __restrict__ W2T,
                                                 const float* __restrict__ b2,
                                                 const unsigned short* __restrict__ hb,
                                                 const float* __restrict__ g_, const float* __restrict__ be_,
                                                 float* __restrict__ out) {
    __shared__ __align__(16) unsigned short sA[32 * 64];    // 4 KB
    __shared__ __align__(16) unsigned short sB[256 * 64];   // 32 KB
    __shared__ float red[2][32][2];
    const int t = threadIdx.x, lane = t & 63, wid = t >> 6;
    const int wm = (wid >> 1) * 16, wn = (wid & 1) * 128;
    const int lr = lane & 15, lq = lane >> 4;
    const int lrow8 = lane >> 3, lseg = lane & 7;
    int m0 = blockIdx.x * 32;

    // A staging: one round, local rows 0..31
    int arl = wid * 8 + lrow8;
    const unsigned short* Ag = t1 + (size_t)(m0 + arl) * 1024 + (((lseg - arl) & 7) * 8);
    unsigned short* sAd = sA + (wid * 8) * 64;
    // B staging: 8 rounds, local rows 0..255 (all of W2T)
    const unsigned short* Bg[8]; unsigned short* sBd[8];
#pragma unroll
    for (int q = 0; q < 8; q++) {
        int rl = q * 32 + wid * 8 + lrow8;
        Bg[q] = W2T + (size_t)rl * 1024 + (((lseg - rl) & 7) * 8);
        sBd[q] = sB + (q * 32 + wid * 8) * 64;
    }
    const unsigned short* sAr = sA + (wm + lr) * 64; int arot = lq + wm + lr;
    const unsigned short* sBr[8]; int brot[8];
#pragma unroll
    for (int j = 0; j < 8; j++) { int br = wn + j * 16 + lr; sBr[j] = sB + br * 64; brot[j] = lq + br; }

    floatx4 acc[8];
#pragma unroll
    for (int j = 0; j < 8; j++) acc[j] = (floatx4){0.f, 0.f, 0.f, 0.f};

    for (int k0 = 0; k0 < 1024; k0 += 64) {
        __syncthreads();
        async_cp16(sAd, Ag + k0);
#pragma unroll
        for (int q = 0; q < 8; q++) async_cp16(sBd[q], Bg[q] + k0);
        __syncthreads();
#pragma unroll
        for (int s = 0; s < 2; s++) {
            bf16x8 af = *(const bf16x8*)(sAr + ((s * 4 + arot) & 7) * 8);
#pragma unroll
            for (int j = 0; j < 8; j++) {
                bf16x8 bfr = *(const bf16x8*)(sBr[j] + ((s * 4 + brot[j]) & 7) * 8);
                acc[j] = __builtin_amdgcn_mfma_f32_16x16x32_bf16(af, bfr, acc[j], 0, 0, 0);
            }
        }
    }
    // v = acc + bias + residual; per-row stats over 256 cols
    float psum[4], psq[4];
#pragma unroll
    for (int r = 0; r < 4; r++) { psum[r] = 0.f; psq[r] = 0.f; }
#pragma unroll
    for (int j = 0; j < 8; j++) {
        int col = wn + j * 16 + lr;
        float bv = b2[col];
#pragma unroll
        for (int r = 0; r < 4; r++) {
            int row = m0 + wm + lq * 4 + r;
            float v = acc[j][r] + bv + bf2f(hb[(size_t)row * 256 + col]);
            acc[j][r] = v;
            psum[r] += v; psq[r] += v * v;
        }
    }
#pragma unroll
    for (int o = 1; o < 16; o <<= 1) {
#pragma unroll
        for (int r = 0; r < 4; r++) { psum[r] += __shfl_xor(psum[r], o); psq[r] += __shfl_xor(psq[r], o); }
    }
    if (lr == 0) {
#pragma unroll
        for (int r = 0; r < 4; r++) {
            int lrow = wm + lq * 4 + r;
            red[wid & 1][lrow][0] = psum[r];
            red[wid & 1][lrow][1] = psq[r];
        }
    }
    __syncthreads();
#pragma unroll
    for (int r = 0; r < 4; r++) {
        int lrow = wm + lq * 4 + r;
        float s = red[0][lrow][0] + red[1][lrow][0];
        float s2 = red[0][lrow][1] + red[1][lrow][1];
        float mu = s * (1.f / 256.f);
        float var = s2 * (1.f / 256.f) - mu * mu;
        float rc = rsqrtf(var + 1e-5f);
        int row = m0 + lrow;
#pragma unroll
        for (int j = 0; j < 8; j++) {
            int col = wn + j * 16 + lr;
            out[(size_t)row * 256 + col] = (acc[j][r] - mu) * rc * g_[col] + be_[col];
        }
    }
}

extern "C" void kernel_launch(void* const* d_in, const int* in_sizes, int n_in,
                              void* d_out, int out_size, void* d_ws, size_t ws_size,
                              hipStream_t stream) {
    const float* x   = (const float*)d_in[0];
    const int*  mask = (const int*)d_in[1];
    const float* W1  = (const float*)d_in[2];
    const float* b1  = (const float*)d_in[3];
    const float* W2  = (const float*)d_in[4];
    const float* b2  = (const float*)d_in[5];
    const float* g1  = (const float*)d_in[6];
    const float* be1 = (const float*)d_in[7];
    const float* g2  = (const float*)d_in[8];
    const float* be2 = (const float*)d_in[9];
    float* out = (float*)d_out;

    char* w = (char*)d_ws;
    unsigned short* mb_   = (unsigned short*)w;  w += 65536 * 2;                 // 128 KB
    unsigned short* E_    = (unsigned short*)w;  w += (size_t)L_ * L_ * 2;       // 8 MB
    unsigned short* XmT_  = (unsigned short*)w;  w += (size_t)1088 * L_ * 2;     // 4.25 MB
    unsigned short* W1T_  = (unsigned short*)w;  w += 262144 * 2;                // 512 KB
    unsigned short* W2T_  = (unsigned short*)w;  w += 262144 * 2;                // 512 KB
    float*          C_    = (float*)w;           w += (size_t)L_ * 1088 * 4;     // 8.5 MB
    unsigned short* hb_   = (unsigned short*)w;  w += (size_t)8192 * 256 * 2;    // 4 MB
    unsigned short* t1_   = (unsigned short*)w;  w += (size_t)8192 * 1024 * 2;   // 16 MB

    k_prep<<<dim3(32, 64, 8), 256, 0, stream>>>(x, W1, W2, mask, mb_, XmT_, W1T_, W2T_);
    k_scores_mfma<<<dim3(32, 16), 256, 0, stream>>>(mb_, E_);
    k_av<<<dim3(17, 32), 256, 0, stream>>>(E_, XmT_, C_);
    k_ln1<<<B_ * L_, 256, 0, stream>>>(x, C_, g1, be1, hb_);
    k_gemm1<<<dim3(16, 64), 256, 0, stream>>>(hb_, W1T_, b1, t1_);
    k_gemm2ln<<<256, 256, 0, stream>>>(t1_, W2T_, b2, hb_, g2, be2, out);
}

// Round 7
// 150.820 us; speedup vs baseline: 3.9748x; 1.0169x over previous
//
#include <hip/hip_runtime.h>
#include <hip/hip_bf16.h>

// SelfAttentionTransformer: B=4, L=2048, D=256, H=8, dk=32, F=1024
// f32 inputs / f32 output. Round 7:
//  - k_av: validated 128x64 MFMA core, N=1088 (rowsum folded as mask cols)
//  - C stored bf16 (halves C traffic)
//  - k_gemm1: 128x128 tile (32 MFMA/barrier, K=256 -> 4 steps)
//  - k_prep: compact 1D grid (2817 blocks, no dead dispatch)

#define B_ 4
#define L_ 2048
#define D_ 256
#define F_ 1024
#define PI_F 3.14159265358979323846f

typedef __bf16 bf16x8 __attribute__((ext_vector_type(8)));
typedef float floatx4 __attribute__((ext_vector_type(4)));

__device__ __forceinline__ unsigned short f2bf(float f) {
    unsigned int u = __float_as_uint(f);
    u = (u + 0x7FFFu + ((u >> 16) & 1u)) >> 16;   // RNE
    return (unsigned short)u;
}
__device__ __forceinline__ float bf2f(unsigned short u) {
    union { unsigned int i; float f; } v; v.i = ((unsigned int)u) << 16; return v.f;
}

__device__ __forceinline__ void async_cp16(unsigned short* lds, const unsigned short* g) {
    __builtin_amdgcn_global_load_lds(
        (const __attribute__((address_space(1))) unsigned int*)g,
        (__attribute__((address_space(3))) unsigned int*)lds, 16, 0, 0);
}

// ---------------- prep, compact 1D grid (2817 blocks):
// [0,2048)   x-transpose(masked) -> XmT rows 0..1023
// [2048,2304) W1T transpose
// [2304,2560) W2T transpose
// [2560,2816) mean -> mb bf16
// 2816        mask rows -> XmT rows 1024..1027
__global__ __launch_bounds__(256) void k_prep(const float* __restrict__ x,
                                              const float* __restrict__ W1,
                                              const float* __restrict__ W2,
                                              const int* __restrict__ mask,
                                              unsigned short* __restrict__ mb,
                                              unsigned short* __restrict__ XmT,
                                              unsigned short* __restrict__ W1T,
                                              unsigned short* __restrict__ W2T) {
    __shared__ float tile[32][33];
    int r = blockIdx.x, t = threadIdx.x;
    if (r >= 2560) {
        if (r < 2816) {
            int idx = (r - 2560) * 256 + t;   // 0..65535
            int l = idx >> 5, k = idx & 31;
            float s = 0.f;
#pragma unroll
            for (int b = 0; b < B_; b++) {
                const float* xp = x + ((size_t)(b * L_ + l)) * D_ + k;
#pragma unroll
                for (int h = 0; h < 8; h++) s += xp[h * 32];
            }
            mb[idx] = f2bf(s * (1.f / 32.f));
        } else {
#pragma unroll
            for (int c = 0; c < 32; c++) {
                int e = c * 256 + t;          // 0..8191
                int b = e >> 11, j = e & (L_ - 1);
                XmT[(size_t)(1024 + b) * L_ + j] = mask[b * L_ + j] ? 0x3F80 : 0;
            }
        }
        return;
    }
    const float* in; unsigned short* outp; int R, C; const int* mrow = nullptr; size_t bo = 0;
    int bx, by;
    if (r < 2048) {
        int z = r >> 9, rem = r & 511; by = rem >> 3; bx = rem & 7;
        in = x; outp = XmT; R = L_; C = 256; bo = (size_t)z * R * C; mrow = mask + z * L_;
    } else if (r < 2304) {
        int rem = r - 2048; bx = rem & 31; by = rem >> 5;
        in = W1; outp = W1T; R = 256; C = 1024;
    } else {
        int rem = r - 2304; bx = rem & 7; by = rem >> 3;
        in = W2; outp = W2T; R = 1024; C = 256;
    }
    int r0 = by * 32, c0 = bx * 32;
    int tx = t & 31, ty = t >> 5;
#pragma unroll
    for (int rr = 0; rr < 4; rr++) {
        int rw = ty + rr * 8;
        tile[rw][tx] = in[bo + (size_t)(r0 + rw) * C + c0 + tx];
    }
    float mfac = 1.f;
    if (mrow) mfac = mrow[r0 + tx] ? 1.f : 0.f;
    __syncthreads();
#pragma unroll
    for (int rr = 0; rr < 4; rr++) {
        int c = ty + rr * 8;
        outp[bo + (size_t)(c0 + c) * R + r0 + tx] = f2bf(tile[tx][c] * mfac);
    }
}

// ---------------- E = exp(sin^2(0.5*clip(m.mT))) via MFMA, bf16 out ----------------
__global__ __launch_bounds__(256) void k_scores_mfma(const unsigned short* __restrict__ mb,
                                                     unsigned short* __restrict__ E) {
    const int t = threadIdx.x, lane = t & 63, wid = t >> 6;
    const int wm = (wid >> 1) * 64, wn = (wid & 1) * 32;
    const int lr = lane & 15, lq = lane >> 4;
    int m0 = blockIdx.y * 128, n0 = blockIdx.x * 64;
    bf16x8 af[4], bfr[2];
#pragma unroll
    for (int i = 0; i < 4; i++)
        af[i] = *(const bf16x8*)(mb + (size_t)(m0 + wm + i * 16 + lr) * 32 + lq * 8);
#pragma unroll
    for (int j = 0; j < 2; j++)
        bfr[j] = *(const bf16x8*)(mb + (size_t)(n0 + wn + j * 16 + lr) * 32 + lq * 8);
    floatx4 acc[4][2];
#pragma unroll
    for (int i = 0; i < 4; i++)
#pragma unroll
        for (int j = 0; j < 2; j++) {
            acc[i][j] = (floatx4){0.f, 0.f, 0.f, 0.f};
            acc[i][j] = __builtin_amdgcn_mfma_f32_16x16x32_bf16(af[i], bfr[j], acc[i][j], 0, 0, 0);
        }
#pragma unroll
    for (int i = 0; i < 4; i++)
#pragma unroll
        for (int j = 0; j < 2; j++)
#pragma unroll
            for (int r = 0; r < 4; r++) {
                int row = m0 + wm + i * 16 + lq * 4 + r;
                int col = n0 + wn + j * 16 + lr;
                float d = fminf(fmaxf(acc[i][j][r], -PI_F), PI_F);
                float sn = __sinf(0.5f * d);
                E[(size_t)row * L_ + col] = f2bf(__expf(sn * sn));
            }
}

// ---------------- validated 128x64 MFMA core (BK=64, async + rotate swizzle) ----------------
__device__ __forceinline__ void mfma_gemm_async(const unsigned short* __restrict__ A,
                                                const unsigned short* __restrict__ Bt,
                                                int K, int m0, int n0,
                                                unsigned short* sA, unsigned short* sB,
                                                floatx4 acc[4][2]) {
    const int t = threadIdx.x;
    const int lane = t & 63, wid = t >> 6;
    const int wm = (wid >> 1) * 64, wn = (wid & 1) * 32;
    const int lr = lane & 15, lq = lane >> 4;
    const int lrow = lane >> 3, lseg = lane & 7;

    const unsigned short* Ag[4]; unsigned short* sAd[4];
#pragma unroll
    for (int q = 0; q < 4; q++) {
        int rl = wid * 32 + q * 8 + lrow;
        int seg = (lseg - rl) & 7;
        Ag[q] = A + (size_t)(m0 + rl) * K + seg * 8;
        sAd[q] = sA + (wid * 32 + q * 8) * 64;
    }
    const unsigned short* Bg[2]; unsigned short* sBd[2];
#pragma unroll
    for (int q = 0; q < 2; q++) {
        int rl = wid * 16 + q * 8 + lrow;
        int seg = (lseg - rl) & 7;
        Bg[q] = Bt + (size_t)(n0 + rl) * K + seg * 8;
        sBd[q] = sB + (wid * 16 + q * 8) * 64;
    }
    int arot[4], brot[2];
    const unsigned short* sAr[4]; const unsigned short* sBr[2];
#pragma unroll
    for (int i = 0; i < 4; i++) { int ar = wm + i * 16 + lr; sAr[i] = sA + ar * 64; arot[i] = lq + ar; }
#pragma unroll
    for (int j = 0; j < 2; j++) { int br = wn + j * 16 + lr; sBr[j] = sB + br * 64; brot[j] = lq + br; }

    for (int k0 = 0; k0 < K; k0 += 64) {
        __syncthreads();
#pragma unroll
        for (int q = 0; q < 4; q++) async_cp16(sAd[q], Ag[q] + k0);
#pragma unroll
        for (int q = 0; q < 2; q++) async_cp16(sBd[q], Bg[q] + k0);
        __syncthreads();
#pragma unroll
        for (int s = 0; s < 2; s++) {
            bf16x8 af[4], bfr[2];
#pragma unroll
            for (int i = 0; i < 4; i++)
                af[i] = *(const bf16x8*)(sAr[i] + ((s * 4 + arot[i]) & 7) * 8);
#pragma unroll
            for (int j = 0; j < 2; j++)
                bfr[j] = *(const bf16x8*)(sBr[j] + ((s * 4 + brot[j]) & 7) * 8);
#pragma unroll
            for (int i = 0; i < 4; i++)
#pragma unroll
                for (int j = 0; j < 2; j++)
                    acc[i][j] = __builtin_amdgcn_mfma_f32_16x16x32_bf16(af[i], bfr[j], acc[i][j], 0, 0, 0);
        }
    }
}

// ---------------- AV: C[2048,1088] = E @ XmT^T (bf16 out) ----------------
__global__ __launch_bounds__(256) void k_av(const unsigned short* __restrict__ E,
                                            const unsigned short* __restrict__ XmT,
                                            unsigned short* __restrict__ Cb) {
    __shared__ __align__(16) unsigned short sA[128 * 64];
    __shared__ __align__(16) unsigned short sB[64 * 64];
    floatx4 acc[4][2];
#pragma unroll
    for (int i = 0; i < 4; i++)
#pragma unroll
        for (int j = 0; j < 2; j++) acc[i][j] = (floatx4){0.f, 0.f, 0.f, 0.f};
    int m0 = blockIdx.y * 128, n0 = blockIdx.x * 64;
    mfma_gemm_async(E, XmT, L_, m0, n0, sA, sB, acc);
    const int lane = threadIdx.x & 63, wid = threadIdx.x >> 6;
    const int wm = (wid >> 1) * 64, wn = (wid & 1) * 32;
    const int lr = lane & 15, lq = lane >> 4;
#pragma unroll
    for (int i = 0; i < 4; i++)
#pragma unroll
        for (int j = 0; j < 2; j++)
#pragma unroll
            for (int r = 0; r < 4; r++) {
                int row = m0 + wm + i * 16 + lq * 4 + r;
                int col = n0 + wn + j * 16 + lr;
                Cb[(size_t)row * 1088 + col] = f2bf(acc[i][j][r]);
            }
}

// ---------------- LN1 fused: v = x + C/rs; LN -> h bf16 ----------------
__global__ __launch_bounds__(256) void k_ln1(const float* __restrict__ x, const unsigned short* __restrict__ Cb,
                                             const float* __restrict__ g_, const float* __restrict__ be_,
                                             unsigned short* __restrict__ hb) {
    int tok = blockIdx.x, t = threadIdx.x;
    int b = tok >> 11, i = tok & (L_ - 1);
    float rs = bf2f(Cb[(size_t)i * 1088 + 1024 + b]);
    float v = x[(size_t)tok * D_ + t] + bf2f(Cb[(size_t)i * 1088 + b * 256 + t]) / rs;
    float s = v, s2 = v * v;
    __shared__ float sm[8];
#pragma unroll
    for (int o = 1; o < 64; o <<= 1) { s += __shfl_xor(s, o); s2 += __shfl_xor(s2, o); }
    if ((t & 63) == 0) { sm[t >> 6] = s; sm[4 + (t >> 6)] = s2; }
    __syncthreads();
    s = sm[0] + sm[1] + sm[2] + sm[3];
    s2 = sm[4] + sm[5] + sm[6] + sm[7];
    float mu = s * (1.f / 256.f);
    float var = s2 * (1.f / 256.f) - mu * mu;
    float r = rsqrtf(var + 1e-5f);
    hb[(size_t)tok * D_ + t] = f2bf((v - mu) * r * g_[t] + be_[t]);
}

// ---------------- GEMM1: t1 = relu(h @ W1 + b1) bf16; 128x128 tile ----------------
__global__ __launch_bounds__(256) void k_gemm1(const unsigned short* __restrict__ hb,
                                               const unsigned short* __restrict__ W1T,
                                               const float* __restrict__ b1, unsigned short* __restrict__ t1) {
    __shared__ __align__(16) unsigned short sA[128 * 64];
    __shared__ __align__(16) unsigned short sB[128 * 64];
    const int t = threadIdx.x, lane = t & 63, wid = t >> 6;
    const int wm = (wid >> 1) * 64, wn = (wid & 1) * 64;
    const int lr = lane & 15, lq = lane >> 4;
    const int lrow8 = lane >> 3, lseg = lane & 7;
    int m0 = blockIdx.y * 128, n0 = blockIdx.x * 128;

    const unsigned short* Ag[4]; unsigned short* sAd[4];
    const unsigned short* Bg[4]; unsigned short* sBd[4];
#pragma unroll
    for (int q = 0; q < 4; q++) {
        int rl = q * 32 + wid * 8 + lrow8;
        int seg = (lseg - rl) & 7;
        Ag[q] = hb + (size_t)(m0 + rl) * 256 + seg * 8;
        Bg[q] = W1T + (size_t)(n0 + rl) * 256 + seg * 8;
        sAd[q] = sA + (q * 32 + wid * 8) * 64;
        sBd[q] = sB + (q * 32 + wid * 8) * 64;
    }
    const unsigned short* sAr[4]; int arot[4];
    const unsigned short* sBr[4]; int brot[4];
#pragma unroll
    for (int i = 0; i < 4; i++) { int ar = wm + i * 16 + lr; sAr[i] = sA + ar * 64; arot[i] = lq + ar; }
#pragma unroll
    for (int j = 0; j < 4; j++) { int br = wn + j * 16 + lr; sBr[j] = sB + br * 64; brot[j] = lq + br; }

    floatx4 acc[4][4];
#pragma unroll
    for (int i = 0; i < 4; i++)
#pragma unroll
        for (int j = 0; j < 4; j++) acc[i][j] = (floatx4){0.f, 0.f, 0.f, 0.f};

    for (int k0 = 0; k0 < 256; k0 += 64) {
        __syncthreads();
#pragma unroll
        for (int q = 0; q < 4; q++) { async_cp16(sAd[q], Ag[q] + k0); async_cp16(sBd[q], Bg[q] + k0); }
        __syncthreads();
#pragma unroll
        for (int s = 0; s < 2; s++) {
            bf16x8 af[4], bfr[4];
#pragma unroll
            for (int i = 0; i < 4; i++) af[i] = *(const bf16x8*)(sAr[i] + ((s * 4 + arot[i]) & 7) * 8);
#pragma unroll
            for (int j = 0; j < 4; j++) bfr[j] = *(const bf16x8*)(sBr[j] + ((s * 4 + brot[j]) & 7) * 8);
#pragma unroll
            for (int i = 0; i < 4; i++)
#pragma unroll
                for (int j = 0; j < 4; j++)
                    acc[i][j] = __builtin_amdgcn_mfma_f32_16x16x32_bf16(af[i], bfr[j], acc[i][j], 0, 0, 0);
        }
    }
    float bb[4];
#pragma unroll
    for (int j = 0; j < 4; j++) bb[j] = b1[n0 + wn + j * 16 + lr];
#pragma unroll
    for (int i = 0; i < 4; i++)
#pragma unroll
        for (int j = 0; j < 4; j++) {
            int col = n0 + wn + j * 16 + lr;
#pragma unroll
            for (int r = 0; r < 4; r++) {
                int row = m0 + wm + i * 16 + lq * 4 + r;
                t1[(size_t)row * 1024 + col] = f2bf(fmaxf(acc[i][j][r] + bb[j], 0.f));
            }
        }
}

// ---------------- GEMM2+LN2 fused: out = LN(h + t1 @ W2 + b2), tile 32 x 256 ----------------
__global__ __launch_bounds__(256) void k_gemm2ln(const unsigned short* __restrict__ t1,
                                                 const unsigned short* __restrict__ W2T,
                                                 const float* __restrict__ b2,
                                                 const unsigned short* __restrict__ hb,
                                                 const float* __restrict__ g_, const float* __restrict__ be_,
                                                 float* __restrict__ out) {
    __shared__ __align__(16) unsigned short sA[32 * 64];    // 4 KB
    __shared__ __align__(16) unsigned short sB[256 * 64];   // 32 KB
    __shared__ float red[2][32][2];
    const int t = threadIdx.x, lane = t & 63, wid = t >> 6;
    const int wm = (wid >> 1) * 16, wn = (wid & 1) * 128;
    const int lr = lane & 15, lq = lane >> 4;
    const int lrow8 = lane >> 3, lseg = lane & 7;
    int m0 = blockIdx.x * 32;

    int arl = wid * 8 + lrow8;
    const unsigned short* Ag = t1 + (size_t)(m0 + arl) * 1024 + (((lseg - arl) & 7) * 8);
    unsigned short* sAd = sA + (wid * 8) * 64;
    const unsigned short* Bg[8]; unsigned short* sBd[8];
#pragma unroll
    for (int q = 0; q < 8; q++) {
        int rl = q * 32 + wid * 8 + lrow8;
        Bg[q] = W2T + (size_t)rl * 1024 + (((lseg - rl) & 7) * 8);
        sBd[q] = sB + (q * 32 + wid * 8) * 64;
    }
    const unsigned short* sAr = sA + (wm + lr) * 64; int arot = lq + wm + lr;
    const unsigned short* sBr[8]; int brot[8];
#pragma unroll
    for (int j = 0; j < 8; j++) { int br = wn + j * 16 + lr; sBr[j] = sB + br * 64; brot[j] = lq + br; }

    floatx4 acc[8];
#pragma unroll
    for (int j = 0; j < 8; j++) acc[j] = (floatx4){0.f, 0.f, 0.f, 0.f};

    for (int k0 = 0; k0 < 1024; k0 += 64) {
        __syncthreads();
        async_cp16(sAd, Ag + k0);
#pragma unroll
        for (int q = 0; q < 8; q++) async_cp16(sBd[q], Bg[q] + k0);
        __syncthreads();
#pragma unroll
        for (int s = 0; s < 2; s++) {
            bf16x8 af = *(const bf16x8*)(sAr + ((s * 4 + arot) & 7) * 8);
#pragma unroll
            for (int j = 0; j < 8; j++) {
                bf16x8 bfr = *(const bf16x8*)(sBr[j] + ((s * 4 + brot[j]) & 7) * 8);
                acc[j] = __builtin_amdgcn_mfma_f32_16x16x32_bf16(af, bfr, acc[j], 0, 0, 0);
            }
        }
    }
    float psum[4], psq[4];
#pragma unroll
    for (int r = 0; r < 4; r++) { psum[r] = 0.f; psq[r] = 0.f; }
#pragma unroll
    for (int j = 0; j < 8; j++) {
        int col = wn + j * 16 + lr;
        float bv = b2[col];
#pragma unroll
        for (int r = 0; r < 4; r++) {
            int row = m0 + wm + lq * 4 + r;
            float v = acc[j][r] + bv + bf2f(hb[(size_t)row * 256 + col]);
            acc[j][r] = v;
            psum[r] += v; psq[r] += v * v;
        }
    }
#pragma unroll
    for (int o = 1; o < 16; o <<= 1) {
#pragma unroll
        for (int r = 0; r < 4; r++) { psum[r] += __shfl_xor(psum[r], o); psq[r] += __shfl_xor(psq[r], o); }
    }
    if (lr == 0) {
#pragma unroll
        for (int r = 0; r < 4; r++) {
            int lrow = wm + lq * 4 + r;
            red[wid & 1][lrow][0] = psum[r];
            red[wid & 1][lrow][1] = psq[r];
        }
    }
    __syncthreads();
#pragma unroll
    for (int r = 0; r < 4; r++) {
        int lrow = wm + lq * 4 + r;
        float s = red[0][lrow][0] + red[1][lrow][0];
        float s2 = red[0][lrow][1] + red[1][lrow][1];
        float mu = s * (1.f / 256.f);
        float var = s2 * (1.f / 256.f) - mu * mu;
        float rc = rsqrtf(var + 1e-5f);
        int row = m0 + lrow;
#pragma unroll
        for (int j = 0; j < 8; j++) {
            int col = wn + j * 16 + lr;
            out[(size_t)row * 256 + col] = (acc[j][r] - mu) * rc * g_[col] + be_[col];
        }
    }
}

extern "C" void kernel_launch(void* const* d_in, const int* in_sizes, int n_in,
                              void* d_out, int out_size, void* d_ws, size_t ws_size,
                              hipStream_t stream) {
    const float* x   = (const float*)d_in[0];
    const int*  mask = (const int*)d_in[1];
    const float* W1  = (const float*)d_in[2];
    const float* b1  = (const float*)d_in[3];
    const float* W2  = (const float*)d_in[4];
    const float* b2  = (const float*)d_in[5];
    const float* g1  = (const float*)d_in[6];
    const float* be1 = (const float*)d_in[7];
    const float* g2  = (const float*)d_in[8];
    const float* be2 = (const float*)d_in[9];
    float* out = (float*)d_out;

    char* w = (char*)d_ws;
    unsigned short* mb_   = (unsigned short*)w;  w += 65536 * 2;                 // 128 KB
    unsigned short* E_    = (unsigned short*)w;  w += (size_t)L_ * L_ * 2;       // 8 MB
    unsigned short* XmT_  = (unsigned short*)w;  w += (size_t)1088 * L_ * 2;     // 4.25 MB
    unsigned short* W1T_  = (unsigned short*)w;  w += 262144 * 2;                // 512 KB
    unsigned short* W2T_  = (unsigned short*)w;  w += 262144 * 2;                // 512 KB
    unsigned short* Cb_   = (unsigned short*)w;  w += (size_t)L_ * 1088 * 2;     // 4.25 MB
    unsigned short* hb_   = (unsigned short*)w;  w += (size_t)8192 * 256 * 2;    // 4 MB
    unsigned short* t1_   = (unsigned short*)w;  w += (size_t)8192 * 1024 * 2;   // 16 MB

    k_prep<<<2817, 256, 0, stream>>>(x, W1, W2, mask, mb_, XmT_, W1T_, W2T_);
    k_scores_mfma<<<dim3(32, 16), 256, 0, stream>>>(mb_, E_);
    k_av<<<dim3(17, 16), 256, 0, stream>>>(E_, XmT_, Cb_);
    k_ln1<<<B_ * L_, 256, 0, stream>>>(x, Cb_, g1, be1, hb_);
    k_gemm1<<<dim3(8, 64), 256, 0, stream>>>(hb_, W1T_, b1, t1_);
    k_gemm2ln<<<256, 256, 0, stream>>>(t1_, W2T_, b2, hb_, g2, be2, out);
}